// Round 10
// baseline (691.657 us; speedup 1.0000x reference)
//
#include <hip/hip_runtime.h>
#include <hip/hip_bf16.h>
#include <cstdint>

#define NV 20000
#define NE 40000
#define NODE_IN 74
#define EDGE_IN 12
#define D 64
#define EHID 128
#define NSTEPS 6

typedef __bf16 bf16x8 __attribute__((ext_vector_type(8)));
typedef float f32x4 __attribute__((ext_vector_type(4)));

// ---------------- node projection: h = relu(nf @ Wp^T + bp); also zero neigh ----------------
__global__ __launch_bounds__(256) void k_proj(const float* __restrict__ nf,
                                              const float* __restrict__ W,
                                              const float* __restrict__ b,
                                              float* __restrict__ h,
                                              float* __restrict__ neigh) {
  __shared__ float sn[4][NODE_IN];
  int tid = threadIdx.x;
  int nb = blockIdx.x * 4;
  for (int idx = tid; idx < 4 * NODE_IN; idx += 256) {
    int r = idx / NODE_IN, c = idx % NODE_IN;
    sn[r][c] = nf[(size_t)(nb + r) * NODE_IN + c];
  }
  __syncthreads();
  int nl = tid >> 6, o = tid & 63;
  float acc = b[o];
#pragma unroll
  for (int i = 0; i < NODE_IN; ++i) acc = fmaf(sn[nl][i], W[o * NODE_IN + i], acc);
  h[(size_t)(nb + nl) * D + o] = fmaxf(acc, 0.f);
  neigh[(size_t)(nb + nl) * D + o] = 0.f;
}

// ------------- edge net layer 1: t = relu(ef @ W1^T + b1), bf16 -------------
__global__ __launch_bounds__(256) void k_edge1(const float* __restrict__ ef,
                                               const float* __restrict__ W1,
                                               const float* __restrict__ b1,
                                               __hip_bfloat16* __restrict__ t_bf) {
  __shared__ float se[2][EDGE_IN];
  int tid = threadIdx.x;
  int eb = blockIdx.x * 2;
  if (tid < 2 * EDGE_IN)
    se[tid / EDGE_IN][tid % EDGE_IN] =
        ef[(size_t)(eb + tid / EDGE_IN) * EDGE_IN + tid % EDGE_IN];
  __syncthreads();
  int el = tid >> 7, k = tid & 127;
  float acc = b1[k];
#pragma unroll
  for (int j = 0; j < EDGE_IN; ++j) acc = fmaf(se[el][j], W1[k * EDGE_IN + j], acc);
  t_bf[(size_t)(eb + el) * EHID + k] = __float2bfloat16(fmaxf(acc, 0.f));
}

// ---------------- W2 fp32 -> bf16 ----------------
__global__ __launch_bounds__(256) void k_cvt_w2(const float* __restrict__ W2,
                                                __hip_bfloat16* __restrict__ w2b) {
  int idx = blockIdx.x * 256 + threadIdx.x;
  if (idx < D * D * EHID) w2b[idx] = __float2bfloat16(W2[idx]);
}

// ---------------- b2 transpose: b2t[o][i] = b2[i*64+o], bf16 ----------------
__global__ __launch_bounds__(256) void k_b2t(const float* __restrict__ b2,
                                             __hip_bfloat16* __restrict__ b2t) {
  int idx = blockIdx.x * 256 + threadIdx.x;  // 4096
  int o = idx >> 6, i = idx & 63;
  b2t[o * 64 + i] = __float2bfloat16(b2[i * 64 + o]);
}

// ------- build GRU B matrix (256 x 128), hi/lo bf16 split -------
__global__ __launch_bounds__(256) void k_build_b(const float* __restrict__ Wih,
                                                 const float* __restrict__ Whh,
                                                 __hip_bfloat16* __restrict__ Bhi,
                                                 __hip_bfloat16* __restrict__ Blo) {
  int idx = blockIdx.x * 256 + threadIdx.x;  // 32768 total
  int n = idx >> 7, k = idx & 127;
  int o = n & 63, cls = n >> 6;
  float v;
  if (cls == 0)      v = (k < 64) ? Wih[o * 64 + k]         : Whh[o * 64 + (k - 64)];
  else if (cls == 1) v = (k < 64) ? Wih[(64 + o) * 64 + k]  : Whh[(64 + o) * 64 + (k - 64)];
  else if (cls == 2) v = (k < 64) ? Wih[(128 + o) * 64 + k] : 0.f;
  else               v = (k < 64) ? 0.f                     : Whh[(128 + o) * 64 + (k - 64)];
  __hip_bfloat16 hi = __float2bfloat16(v);
  Bhi[idx] = hi;
  Blo[idx] = __float2bfloat16(v - __bfloat162float(hi));
}

// ------- fused NNConv message+aggregate: W2-slice persistent in LDS -------
// Grid: 256 blocks = cg(4 colgroups of 16) x ih(2 i-halves of 32) x s(32 stripes
// of 1280 edges). 512 threads = 4 teams x 2 waves. R10: each WAVE covers its
// team's full 64-edge tile (M=4 m-tiles -> 16 MFMA per 4 B-frag reads, 2x the
// amortization) and the two waves of a team split the i-range (ihw=0: ig 0-15,
// ihw=1: 16-31; partial sums merge via the existing atomics; b2-term added by
// ihw=0 only). Inner loop: 4 ds_read_b128 + 4 ds_read_b64 + 16 MFMA, no global,
// no barriers.
__global__ __launch_bounds__(512, 2) void k_msg(const float* __restrict__ h,
                                                const __hip_bfloat16* __restrict__ t_bf,
                                                const __hip_bfloat16* __restrict__ w2,
                                                const __hip_bfloat16* __restrict__ b2t,
                                                const int* __restrict__ src,
                                                const int* __restrict__ dst,
                                                float* __restrict__ neigh) {
  __shared__ __hip_bfloat16 W2s[512 * 128];      // 128 KB, row = ig*16+ol, swizzled k-chunks
  __shared__ __hip_bfloat16 Hs[4][32 * 64];      // 16 KB, [team][ig][e_local] bf16
  int tid = threadIdx.x;
  int bx = blockIdx.x;
  int cg = bx >> 6, ih = (bx >> 5) & 1, s = bx & 31;
  int lane = tid & 63, lr = lane & 15, lq = lane >> 4;
  int wave = tid >> 6;
  int team = wave >> 1, ihw = wave & 1;
  int lane128 = tid & 127;
  const int ocol = cg * 16 + lr;

  // ---- load W2 slice into LDS (once) ----
#pragma unroll
  for (int it = 0; it < 16; ++it) {
    int chunk = it * 512 + tid;          // 8192 chunks of 8 elems
    int row = chunk >> 4, c = chunk & 15;
    int ig = row >> 4, ol = row & 15;
    const __hip_bfloat16* gp =
        w2 + ((size_t)((ih * 32 + ig) * 64 + cg * 16 + ol)) * EHID + c * 8;
    *(bf16x8*)(W2s + row * 128 + ((c ^ ol) * 8)) = *(const bf16x8*)gp;
  }
  // loop-invariant b2 B-frag (used by ihw==0 only)
  bf16x8 b2frag = *(const bf16x8*)(b2t + (size_t)ocol * 64 + ih * 32 + lq * 8);

  int nt = (s < 31) ? 20 : 5;  // full 64-edge tiles in this stripe (40000 = 31*1280+320)

#pragma unroll 1
  for (int r5 = 0; r5 < 5; ++r5) {
    int t = r5 * 4 + team;
    int e0t = s * 1280 + t * 64;
    bool valid = (t < nt);
    __syncthreads();  // previous round's readers done before overwriting Hs
    if (valid) {
      // gather h[src] for this tile -> Hs[team][ig][e], bf16 (both waves of team)
      int e_l = lane128 & 63, hh = lane128 >> 6;
      int s_e = src[e0t + e_l];
      const float* hrow = h + (size_t)s_e * D + ih * 32 + hh * 16;
#pragma unroll
      for (int j4 = 0; j4 < 4; ++j4) {
        float4 hv = *(const float4*)(hrow + j4 * 4);
        int i0 = hh * 16 + j4 * 4;
        Hs[team][(i0 + 0) * 64 + e_l] = __float2bfloat16(hv.x);
        Hs[team][(i0 + 1) * 64 + e_l] = __float2bfloat16(hv.y);
        Hs[team][(i0 + 2) * 64 + e_l] = __float2bfloat16(hv.z);
        Hs[team][(i0 + 3) * 64 + e_l] = __float2bfloat16(hv.w);
      }
    }
    __syncthreads();  // Hs ready
    if (!valid) continue;

    const __hip_bfloat16* Ht = Hs[team];
    // t-frags for all 4 m-tiles (full 64-edge tile per wave)
    bf16x8 tf[4][4];
#pragma unroll
    for (int mt = 0; mt < 4; ++mt)
#pragma unroll
      for (int ks = 0; ks < 4; ++ks)
        tf[mt][ks] = *(const bf16x8*)(t_bf + (size_t)(e0t + mt * 16 + lr) * EHID +
                                      ks * 32 + lq * 8);
    // C init: b2-term (once per tile, by ihw==0) via one MFMA per m-tile
    f32x4 C[4];
    if (ihw == 0) {
#pragma unroll
      for (int mt = 0; mt < 4; ++mt) {
        bf16x8 af;
#pragma unroll
        for (int j = 0; j < 8; ++j)
          af[j] = *(const __bf16*)(Ht + (lq * 8 + j) * 64 + mt * 16 + lr);
        f32x4 z = {0.f, 0.f, 0.f, 0.f};
        C[mt] = __builtin_amdgcn_mfma_f32_16x16x32_bf16(af, b2frag, z, 0, 0, 0);
      }
    } else {
#pragma unroll
      for (int mt = 0; mt < 4; ++mt) C[mt] = f32x4{0.f, 0.f, 0.f, 0.f};
    }
    // swizzled per-lane k-chunk offsets
    int sw0 = (((0 * 4 + lq) ^ lr) * 8);
    int sw1 = (((1 * 4 + lq) ^ lr) * 8);
    int sw2 = (((2 * 4 + lq) ^ lr) * 8);
    int sw3 = (((3 * 4 + lq) ^ lr) * 8);

#pragma unroll 2
    for (int igl = 0; igl < 16; ++igl) {
      int ig = ihw * 16 + igl;
      const __hip_bfloat16* Wr = W2s + (ig * 16 + lr) * 128;
      bf16x8 f0 = *(const bf16x8*)(Wr + sw0);
      bf16x8 f1 = *(const bf16x8*)(Wr + sw1);
      bf16x8 f2 = *(const bf16x8*)(Wr + sw2);
      bf16x8 f3 = *(const bf16x8*)(Wr + sw3);
#pragma unroll
      for (int mt = 0; mt < 4; ++mt) {
        f32x4 P = {0.f, 0.f, 0.f, 0.f};
        P = __builtin_amdgcn_mfma_f32_16x16x32_bf16(tf[mt][0], f0, P, 0, 0, 0);
        P = __builtin_amdgcn_mfma_f32_16x16x32_bf16(tf[mt][1], f1, P, 0, 0, 0);
        P = __builtin_amdgcn_mfma_f32_16x16x32_bf16(tf[mt][2], f2, P, 0, 0, 0);
        P = __builtin_amdgcn_mfma_f32_16x16x32_bf16(tf[mt][3], f3, P, 0, 0, 0);
        uint2 hA = *(const uint2*)(Ht + ig * 64 + mt * 16 + lq * 4);
        C[mt][0] = fmaf(__uint_as_float(hA.x << 16), P[0], C[mt][0]);
        C[mt][1] = fmaf(__uint_as_float(hA.x & 0xffff0000u), P[1], C[mt][1]);
        C[mt][2] = fmaf(__uint_as_float(hA.y << 16), P[2], C[mt][2]);
        C[mt][3] = fmaf(__uint_as_float(hA.y & 0xffff0000u), P[3], C[mt][3]);
      }
    }
    // scatter-add partials (i-halves and parities merge via atomics)
#pragma unroll
    for (int mt = 0; mt < 4; ++mt) {
#pragma unroll
      for (int r = 0; r < 4; ++r) {
        int ea = e0t + mt * 16 + lq * 4 + r;
        atomicAdd(neigh + (size_t)dst[ea] * D + ocol, C[mt][r]);
      }
    }
  }
}

// ------- GRU: 32 nodes/block (R8 version — 64-node variant was ~7 µs/step slower) -------
__global__ __launch_bounds__(256) void k_gru(float* __restrict__ neigh,
                                             float* __restrict__ h,
                                             const __hip_bfloat16* __restrict__ Bhi,
                                             const __hip_bfloat16* __restrict__ Blo,
                                             const float* __restrict__ cb,
                                             const float* __restrict__ bih,
                                             const float* __restrict__ bhh) {
  __shared__ __hip_bfloat16 Ahi[32 * 128];
  __shared__ __hip_bfloat16 Alo[32 * 128];
  int tid = threadIdx.x;
  int n0 = blockIdx.x * 32;  // NV % 32 == 0
  for (int idx = tid; idx < 32 * 64; idx += 256) {
    int node = idx >> 6, f = idx & 63;
    int gn = n0 + node;
    float xv = fmaxf(neigh[(size_t)gn * D + f] + cb[f], 0.f);
    neigh[(size_t)gn * D + f] = 0.f;
    float hv = h[(size_t)gn * D + f];
    __hip_bfloat16 xh = __float2bfloat16(xv);
    __hip_bfloat16 hh = __float2bfloat16(hv);
    Ahi[node * 128 + f] = xh;
    Ahi[node * 128 + 64 + f] = hh;
    Alo[node * 128 + f] = __float2bfloat16(xv - __bfloat162float(xh));
    Alo[node * 128 + 64 + f] = __float2bfloat16(hv - __bfloat162float(hh));
  }
  __syncthreads();
  int wave = tid >> 6, lane = tid & 63;
  int lr = lane & 15, lq = lane >> 4;
  f32x4 acc[2][4] = {};
#pragma unroll
  for (int ks = 0; ks < 4; ++ks) {
    int koff = ks * 32 + lq * 8;
    bf16x8 ah[2], al[2], bh[4], bl[4];
#pragma unroll
    for (int mt = 0; mt < 2; ++mt) {
      ah[mt] = *(const bf16x8*)(Ahi + (mt * 16 + lr) * 128 + koff);
      al[mt] = *(const bf16x8*)(Alo + (mt * 16 + lr) * 128 + koff);
    }
#pragma unroll
    for (int cls = 0; cls < 4; ++cls) {
      int n = cls * 64 + wave * 16 + lr;
      bh[cls] = *(const bf16x8*)(Bhi + (size_t)n * 128 + koff);
      bl[cls] = *(const bf16x8*)(Blo + (size_t)n * 128 + koff);
    }
#pragma unroll
    for (int mt = 0; mt < 2; ++mt)
#pragma unroll
      for (int cls = 0; cls < 4; ++cls) {
        acc[mt][cls] = __builtin_amdgcn_mfma_f32_16x16x32_bf16(ah[mt], bh[cls], acc[mt][cls], 0, 0, 0);
        acc[mt][cls] = __builtin_amdgcn_mfma_f32_16x16x32_bf16(al[mt], bh[cls], acc[mt][cls], 0, 0, 0);
        acc[mt][cls] = __builtin_amdgcn_mfma_f32_16x16x32_bf16(ah[mt], bl[cls], acc[mt][cls], 0, 0, 0);
      }
  }
  int o = wave * 16 + lr;
  float b_r = bih[o] + bhh[o];
  float b_z = bih[64 + o] + bhh[64 + o];
  float b_in = bih[128 + o];
  float b_hn = bhh[128 + o];
#pragma unroll
  for (int mt = 0; mt < 2; ++mt) {
#pragma unroll
    for (int r = 0; r < 4; ++r) {
      int gn = n0 + mt * 16 + lq * 4 + r;
      float rs = acc[mt][0][r] + b_r;
      float zs = acc[mt][1][r] + b_z;
      float inn = acc[mt][2][r] + b_in;
      float hnn = acc[mt][3][r] + b_hn;
      float rg = 1.f / (1.f + __expf(-rs));
      float zg = 1.f / (1.f + __expf(-zs));
      float a = inn + rg * hnn;
      a = fminf(fmaxf(a, -15.f), 15.f);
      float e2 = __expf(2.f * a);
      float nn = (e2 - 1.f) / (e2 + 1.f);
      float hold = h[(size_t)gn * D + o];
      h[(size_t)gn * D + o] = (1.f - zg) * nn + zg * hold;
    }
  }
}

// ---------------- predictor: score_e = [h_src | h_dst] . pW + pb ----------------
__global__ __launch_bounds__(256) void k_pred(const float* __restrict__ h,
                                              const int* __restrict__ src,
                                              const int* __restrict__ dst,
                                              const float* __restrict__ pW,
                                              const float* __restrict__ pb,
                                              float* __restrict__ out) {
  int wave = threadIdx.x >> 6, lane = threadIdx.x & 63;
  int e = blockIdx.x * 4 + wave;
  int s = src[e], d2 = dst[e];
  float v = h[(size_t)s * D + lane] * pW[lane] + h[(size_t)d2 * D + lane] * pW[64 + lane];
#pragma unroll
  for (int off = 32; off >= 1; off >>= 1) v += __shfl_xor(v, off, 64);
  if (lane == 0) out[e] = v + pb[0];
}

extern "C" void kernel_launch(void* const* d_in, const int* in_sizes, int n_in,
                              void* d_out, int out_size, void* d_ws, size_t ws_size,
                              hipStream_t stream) {
  const float* node_feats = (const float*)d_in[0];
  const float* edge_feats = (const float*)d_in[1];
  const int* src = (const int*)d_in[2];
  const int* dst = (const int*)d_in[3];
  const float* proj_W = (const float*)d_in[4];
  const float* proj_b = (const float*)d_in[5];
  const float* en_W1 = (const float*)d_in[6];
  const float* en_b1 = (const float*)d_in[7];
  const float* en_W2 = (const float*)d_in[8];
  const float* en_b2 = (const float*)d_in[9];
  const float* conv_b = (const float*)d_in[10];
  const float* gru_Wih = (const float*)d_in[11];
  const float* gru_Whh = (const float*)d_in[12];
  const float* gru_bih = (const float*)d_in[13];
  const float* gru_bhh = (const float*)d_in[14];
  const float* pred_W = (const float*)d_in[15];
  const float* pred_b = (const float*)d_in[16];

  char* ws = (char*)d_ws;
  size_t off = 0;
  auto walloc = [&](size_t bytes) -> void* {
    void* p = ws + off;
    off = (off + bytes + 255) & ~(size_t)255;
    return p;
  };
  float* h = (float*)walloc((size_t)NV * D * 4);
  float* neigh = (float*)walloc((size_t)NV * D * 4);
  __hip_bfloat16* t_bf = (__hip_bfloat16*)walloc((size_t)NE * EHID * 2);
  __hip_bfloat16* w2_bf = (__hip_bfloat16*)walloc((size_t)D * D * EHID * 2);
  __hip_bfloat16* b2t = (__hip_bfloat16*)walloc((size_t)D * D * 2);
  __hip_bfloat16* Bhi = (__hip_bfloat16*)walloc((size_t)256 * 128 * 2);
  __hip_bfloat16* Blo = (__hip_bfloat16*)walloc((size_t)256 * 128 * 2);

  k_proj<<<NV / 4, 256, 0, stream>>>(node_feats, proj_W, proj_b, h, neigh);
  k_edge1<<<NE / 2, 256, 0, stream>>>(edge_feats, en_W1, en_b1, t_bf);
  k_cvt_w2<<<(D * D * EHID + 255) / 256, 256, 0, stream>>>(en_W2, w2_bf);
  k_b2t<<<(D * D + 255) / 256, 256, 0, stream>>>(en_b2, b2t);
  k_build_b<<<128, 256, 0, stream>>>(gru_Wih, gru_Whh, Bhi, Blo);
  for (int s = 0; s < NSTEPS; ++s) {
    k_msg<<<256, 512, 0, stream>>>(h, t_bf, w2_bf, b2t, src, dst, neigh);
    k_gru<<<NV / 32, 256, 0, stream>>>(neigh, h, Bhi, Blo, conv_b, gru_bih, gru_bhh);
  }
  k_pred<<<NE / 4, 256, 0, stream>>>(h, src, dst, pred_W, pred_b, (float*)d_out);
}

// Round 11
// 500.795 us; speedup vs baseline: 1.3811x; 1.3811x over previous
//
#include <hip/hip_runtime.h>
#include <hip/hip_bf16.h>
#include <cstdint>

#define NV 20000
#define NE 40000
#define NODE_IN 74
#define EDGE_IN 12
#define D 64
#define EHID 128
#define NSTEPS 6

typedef __bf16 bf16x8 __attribute__((ext_vector_type(8)));
typedef float f32x4 __attribute__((ext_vector_type(4)));

// ---------------- node projection: h = relu(nf @ Wp^T + bp); also zero neigh ----------------
__global__ __launch_bounds__(256) void k_proj(const float* __restrict__ nf,
                                              const float* __restrict__ W,
                                              const float* __restrict__ b,
                                              float* __restrict__ h,
                                              float* __restrict__ neigh) {
  __shared__ float sn[4][NODE_IN];
  int tid = threadIdx.x;
  int nb = blockIdx.x * 4;
  for (int idx = tid; idx < 4 * NODE_IN; idx += 256) {
    int r = idx / NODE_IN, c = idx % NODE_IN;
    sn[r][c] = nf[(size_t)(nb + r) * NODE_IN + c];
  }
  __syncthreads();
  int nl = tid >> 6, o = tid & 63;
  float acc = b[o];
#pragma unroll
  for (int i = 0; i < NODE_IN; ++i) acc = fmaf(sn[nl][i], W[o * NODE_IN + i], acc);
  h[(size_t)(nb + nl) * D + o] = fmaxf(acc, 0.f);
  neigh[(size_t)(nb + nl) * D + o] = 0.f;
}

// ------------- edge net layer 1: t = relu(ef @ W1^T + b1), bf16 -------------
__global__ __launch_bounds__(256) void k_edge1(const float* __restrict__ ef,
                                               const float* __restrict__ W1,
                                               const float* __restrict__ b1,
                                               __hip_bfloat16* __restrict__ t_bf) {
  __shared__ float se[2][EDGE_IN];
  int tid = threadIdx.x;
  int eb = blockIdx.x * 2;
  if (tid < 2 * EDGE_IN)
    se[tid / EDGE_IN][tid % EDGE_IN] =
        ef[(size_t)(eb + tid / EDGE_IN) * EDGE_IN + tid % EDGE_IN];
  __syncthreads();
  int el = tid >> 7, k = tid & 127;
  float acc = b1[k];
#pragma unroll
  for (int j = 0; j < EDGE_IN; ++j) acc = fmaf(se[el][j], W1[k * EDGE_IN + j], acc);
  t_bf[(size_t)(eb + el) * EHID + k] = __float2bfloat16(fmaxf(acc, 0.f));
}

// ---------------- W2 fp32 -> bf16 ----------------
__global__ __launch_bounds__(256) void k_cvt_w2(const float* __restrict__ W2,
                                                __hip_bfloat16* __restrict__ w2b) {
  int idx = blockIdx.x * 256 + threadIdx.x;
  if (idx < D * D * EHID) w2b[idx] = __float2bfloat16(W2[idx]);
}

// ---------------- b2 transpose: b2t[o][i] = b2[i*64+o], bf16 ----------------
__global__ __launch_bounds__(256) void k_b2t(const float* __restrict__ b2,
                                             __hip_bfloat16* __restrict__ b2t) {
  int idx = blockIdx.x * 256 + threadIdx.x;  // 4096
  int o = idx >> 6, i = idx & 63;
  b2t[o * 64 + i] = __float2bfloat16(b2[i * 64 + o]);
}

// ------- build GRU B matrix (256 x 128), hi/lo bf16 split -------
__global__ __launch_bounds__(256) void k_build_b(const float* __restrict__ Wih,
                                                 const float* __restrict__ Whh,
                                                 __hip_bfloat16* __restrict__ Bhi,
                                                 __hip_bfloat16* __restrict__ Blo) {
  int idx = blockIdx.x * 256 + threadIdx.x;  // 32768 total
  int n = idx >> 7, k = idx & 127;
  int o = n & 63, cls = n >> 6;
  float v;
  if (cls == 0)      v = (k < 64) ? Wih[o * 64 + k]         : Whh[o * 64 + (k - 64)];
  else if (cls == 1) v = (k < 64) ? Wih[(64 + o) * 64 + k]  : Whh[(64 + o) * 64 + (k - 64)];
  else if (cls == 2) v = (k < 64) ? Wih[(128 + o) * 64 + k] : 0.f;
  else               v = (k < 64) ? 0.f                     : Whh[(128 + o) * 64 + (k - 64)];
  __hip_bfloat16 hi = __float2bfloat16(v);
  Bhi[idx] = hi;
  Blo[idx] = __float2bfloat16(v - __bfloat162float(hi));
}

// ------- fused NNConv message+aggregate: LDS-persistent W2, barrier-free tiles -------
// Grid: 256 blocks = cg(4 colgroups of 16) x ih(2 i-halves of 32) x s(32 stripes of
// 1280 edges = 20 tiles). 512 threads = 8 waves. Each WAVE owns whole 64-edge tiles
// (4 m-tiles -> 16 MFMA per 4 B-frag reads; tiles w, w+8, w+16) over the block's
// full 32-i range (atomic count = R9 level, NOT R10's 2x). Hs is WAVE-PRIVATE
// (16-i phase buffer): after the one W2s-load barrier the loop is barrier-free —
// atomic drain overlaps the next tile's gather. b2-term: phase-masked b2 frags.
__global__ __launch_bounds__(512, 2) void k_msg(const float* __restrict__ h,
                                                const __hip_bfloat16* __restrict__ t_bf,
                                                const __hip_bfloat16* __restrict__ w2,
                                                const __hip_bfloat16* __restrict__ b2t,
                                                const int* __restrict__ src,
                                                const int* __restrict__ dst,
                                                float* __restrict__ neigh) {
  __shared__ __hip_bfloat16 W2s[512 * 128];   // 128 KB, row = ig*16+ol, swizzled k-chunks
  __shared__ __hip_bfloat16 Hs[8][16 * 64];   // 16 KB, per-wave [i_phase][e] bf16
  int tid = threadIdx.x;
  int bx = blockIdx.x;
  int cg = bx >> 6, ih = (bx >> 5) & 1, s = bx & 31;
  int lane = tid & 63, lr = lane & 15, lq = lane >> 4;
  int wave = tid >> 6;
  const int ocol = cg * 16 + lr;

  // ---- load W2 slice into LDS (once) ----
#pragma unroll
  for (int it = 0; it < 16; ++it) {
    int chunk = it * 512 + tid;          // 8192 chunks of 8 elems
    int row = chunk >> 4, c = chunk & 15;
    int ig = row >> 4, ol = row & 15;
    const __hip_bfloat16* gp =
        w2 + ((size_t)((ih * 32 + ig) * 64 + cg * 16 + ol)) * EHID + c * 8;
    *(bf16x8*)(W2s + row * 128 + ((c ^ ol) * 8)) = *(const bf16x8*)gp;
  }
  // phase-masked b2 B-frags (k = lq*8+j over this block's 32-i slice)
  bf16x8 b2f0, b2f1;
#pragma unroll
  for (int j = 0; j < 8; ++j) {
    int k = lq * 8 + j;
    __bf16 v = *(const __bf16*)(b2t + (size_t)ocol * 64 + ih * 32 + k);
    __bf16 z = (__bf16)0.0f;
    b2f0[j] = (k < 16) ? v : z;
    b2f1[j] = (k >= 16) ? v : z;
  }
  __syncthreads();  // W2s ready — the ONLY barrier

  __hip_bfloat16* Hsw = &Hs[wave][0];
  int e0s = s * 1280;
  int nt = (s < 31) ? 20 : 5;  // 40000 = 31*1280 + 320

  // swizzled per-lane k-chunk offsets
  int sw0 = (((0 * 4 + lq) ^ lr) * 8);
  int sw1 = (((1 * 4 + lq) ^ lr) * 8);
  int sw2 = (((2 * 4 + lq) ^ lr) * 8);
  int sw3 = (((3 * 4 + lq) ^ lr) * 8);

#pragma unroll 1
  for (int r3 = 0; r3 < 3; ++r3) {
    int t = r3 * 8 + wave;
    if (t >= nt) break;     // divergence is fine: no barriers below
    int e0t = e0s + t * 64;

    // t-frags for this tile's 4 m-tiles
    bf16x8 tf[4][4];
#pragma unroll
    for (int mt = 0; mt < 4; ++mt)
#pragma unroll
      for (int ks = 0; ks < 4; ++ks)
        tf[mt][ks] = *(const bf16x8*)(t_bf + (size_t)(e0t + mt * 16 + lr) * EHID +
                                      ks * 32 + lq * 8);

    int s_e = src[e0t + lane];
    const float* hrow = h + (size_t)s_e * D + ih * 32;
    f32x4 C[4];
#pragma unroll
    for (int mt = 0; mt < 4; ++mt) C[mt] = f32x4{0.f, 0.f, 0.f, 0.f};

#pragma unroll
    for (int ph = 0; ph < 2; ++ph) {
      // gather this phase's 16 i's for all 64 edges (wave-private; no barrier)
#pragma unroll
      for (int q = 0; q < 4; ++q) {
        float4 hv = *(const float4*)(hrow + ph * 16 + q * 4);
        Hsw[(q * 4 + 0) * 64 + lane] = __float2bfloat16(hv.x);
        Hsw[(q * 4 + 1) * 64 + lane] = __float2bfloat16(hv.y);
        Hsw[(q * 4 + 2) * 64 + lane] = __float2bfloat16(hv.z);
        Hsw[(q * 4 + 3) * 64 + lane] = __float2bfloat16(hv.w);
      }
      // b2-term partial for this phase (masked frag zeroes out-of-phase k)
#pragma unroll
      for (int mt = 0; mt < 4; ++mt) {
        bf16x8 af;
#pragma unroll
        for (int j = 0; j < 8; ++j)
          af[j] = *(const __bf16*)(Hsw + ((lq * 8 + j) & 15) * 64 + mt * 16 + lr);
        C[mt] = __builtin_amdgcn_mfma_f32_16x16x32_bf16(af, ph ? b2f1 : b2f0, C[mt], 0, 0, 0);
      }
      // inner: 16 i's of this phase
#pragma unroll 2
      for (int igl = 0; igl < 16; ++igl) {
        int ig = ph * 16 + igl;
        const __hip_bfloat16* Wr = W2s + (ig * 16 + lr) * 128;
        bf16x8 f0 = *(const bf16x8*)(Wr + sw0);
        bf16x8 f1 = *(const bf16x8*)(Wr + sw1);
        bf16x8 f2 = *(const bf16x8*)(Wr + sw2);
        bf16x8 f3 = *(const bf16x8*)(Wr + sw3);
#pragma unroll
        for (int mt = 0; mt < 4; ++mt) {
          f32x4 P = {0.f, 0.f, 0.f, 0.f};
          P = __builtin_amdgcn_mfma_f32_16x16x32_bf16(tf[mt][0], f0, P, 0, 0, 0);
          P = __builtin_amdgcn_mfma_f32_16x16x32_bf16(tf[mt][1], f1, P, 0, 0, 0);
          P = __builtin_amdgcn_mfma_f32_16x16x32_bf16(tf[mt][2], f2, P, 0, 0, 0);
          P = __builtin_amdgcn_mfma_f32_16x16x32_bf16(tf[mt][3], f3, P, 0, 0, 0);
          uint2 hA = *(const uint2*)(Hsw + igl * 64 + mt * 16 + lq * 4);
          C[mt][0] = fmaf(__uint_as_float(hA.x << 16), P[0], C[mt][0]);
          C[mt][1] = fmaf(__uint_as_float(hA.x & 0xffff0000u), P[1], C[mt][1]);
          C[mt][2] = fmaf(__uint_as_float(hA.y << 16), P[2], C[mt][2]);
          C[mt][3] = fmaf(__uint_as_float(hA.y & 0xffff0000u), P[3], C[mt][3]);
        }
      }
    }
    // scatter-add (i-halves merge via atomics); overlaps next tile (no barrier)
#pragma unroll
    for (int mt = 0; mt < 4; ++mt) {
#pragma unroll
      for (int r = 0; r < 4; ++r) {
        int ea = e0t + mt * 16 + lq * 4 + r;
        atomicAdd(neigh + (size_t)dst[ea] * D + ocol, C[mt][r]);
      }
    }
  }
}

// ------- GRU: 32 nodes/block (proven best shape); re-zeroes neigh -------
__global__ __launch_bounds__(256) void k_gru(float* __restrict__ neigh,
                                             float* __restrict__ h,
                                             const __hip_bfloat16* __restrict__ Bhi,
                                             const __hip_bfloat16* __restrict__ Blo,
                                             const float* __restrict__ cb,
                                             const float* __restrict__ bih,
                                             const float* __restrict__ bhh) {
  __shared__ __hip_bfloat16 Ahi[32 * 128];
  __shared__ __hip_bfloat16 Alo[32 * 128];
  int tid = threadIdx.x;
  int n0 = blockIdx.x * 32;  // NV % 32 == 0
  for (int idx = tid; idx < 32 * 64; idx += 256) {
    int node = idx >> 6, f = idx & 63;
    int gn = n0 + node;
    float xv = fmaxf(neigh[(size_t)gn * D + f] + cb[f], 0.f);
    neigh[(size_t)gn * D + f] = 0.f;
    float hv = h[(size_t)gn * D + f];
    __hip_bfloat16 xh = __float2bfloat16(xv);
    __hip_bfloat16 hh = __float2bfloat16(hv);
    Ahi[node * 128 + f] = xh;
    Ahi[node * 128 + 64 + f] = hh;
    Alo[node * 128 + f] = __float2bfloat16(xv - __bfloat162float(xh));
    Alo[node * 128 + 64 + f] = __float2bfloat16(hv - __bfloat162float(hh));
  }
  __syncthreads();
  int wave = tid >> 6, lane = tid & 63;
  int lr = lane & 15, lq = lane >> 4;
  f32x4 acc[2][4] = {};
#pragma unroll
  for (int ks = 0; ks < 4; ++ks) {
    int koff = ks * 32 + lq * 8;
    bf16x8 ah[2], al[2], bh[4], bl[4];
#pragma unroll
    for (int mt = 0; mt < 2; ++mt) {
      ah[mt] = *(const bf16x8*)(Ahi + (mt * 16 + lr) * 128 + koff);
      al[mt] = *(const bf16x8*)(Alo + (mt * 16 + lr) * 128 + koff);
    }
#pragma unroll
    for (int cls = 0; cls < 4; ++cls) {
      int n = cls * 64 + wave * 16 + lr;
      bh[cls] = *(const bf16x8*)(Bhi + (size_t)n * 128 + koff);
      bl[cls] = *(const bf16x8*)(Blo + (size_t)n * 128 + koff);
    }
#pragma unroll
    for (int mt = 0; mt < 2; ++mt)
#pragma unroll
      for (int cls = 0; cls < 4; ++cls) {
        acc[mt][cls] = __builtin_amdgcn_mfma_f32_16x16x32_bf16(ah[mt], bh[cls], acc[mt][cls], 0, 0, 0);
        acc[mt][cls] = __builtin_amdgcn_mfma_f32_16x16x32_bf16(al[mt], bh[cls], acc[mt][cls], 0, 0, 0);
        acc[mt][cls] = __builtin_amdgcn_mfma_f32_16x16x32_bf16(ah[mt], bl[cls], acc[mt][cls], 0, 0, 0);
      }
  }
  int o = wave * 16 + lr;
  float b_r = bih[o] + bhh[o];
  float b_z = bih[64 + o] + bhh[64 + o];
  float b_in = bih[128 + o];
  float b_hn = bhh[128 + o];
#pragma unroll
  for (int mt = 0; mt < 2; ++mt) {
#pragma unroll
    for (int r = 0; r < 4; ++r) {
      int gn = n0 + mt * 16 + lq * 4 + r;
      float rs = acc[mt][0][r] + b_r;
      float zs = acc[mt][1][r] + b_z;
      float inn = acc[mt][2][r] + b_in;
      float hnn = acc[mt][3][r] + b_hn;
      float rg = 1.f / (1.f + __expf(-rs));
      float zg = 1.f / (1.f + __expf(-zs));
      float a = inn + rg * hnn;
      a = fminf(fmaxf(a, -15.f), 15.f);
      float e2 = __expf(2.f * a);
      float nn = (e2 - 1.f) / (e2 + 1.f);
      float hold = h[(size_t)gn * D + o];
      h[(size_t)gn * D + o] = (1.f - zg) * nn + zg * hold;
    }
  }
}

// ---------------- predictor: score_e = [h_src | h_dst] . pW + pb ----------------
__global__ __launch_bounds__(256) void k_pred(const float* __restrict__ h,
                                              const int* __restrict__ src,
                                              const int* __restrict__ dst,
                                              const float* __restrict__ pW,
                                              const float* __restrict__ pb,
                                              float* __restrict__ out) {
  int wave = threadIdx.x >> 6, lane = threadIdx.x & 63;
  int e = blockIdx.x * 4 + wave;
  int s = src[e], d2 = dst[e];
  float v = h[(size_t)s * D + lane] * pW[lane] + h[(size_t)d2 * D + lane] * pW[64 + lane];
#pragma unroll
  for (int off = 32; off >= 1; off >>= 1) v += __shfl_xor(v, off, 64);
  if (lane == 0) out[e] = v + pb[0];
}

extern "C" void kernel_launch(void* const* d_in, const int* in_sizes, int n_in,
                              void* d_out, int out_size, void* d_ws, size_t ws_size,
                              hipStream_t stream) {
  const float* node_feats = (const float*)d_in[0];
  const float* edge_feats = (const float*)d_in[1];
  const int* src = (const int*)d_in[2];
  const int* dst = (const int*)d_in[3];
  const float* proj_W = (const float*)d_in[4];
  const float* proj_b = (const float*)d_in[5];
  const float* en_W1 = (const float*)d_in[6];
  const float* en_b1 = (const float*)d_in[7];
  const float* en_W2 = (const float*)d_in[8];
  const float* en_b2 = (const float*)d_in[9];
  const float* conv_b = (const float*)d_in[10];
  const float* gru_Wih = (const float*)d_in[11];
  const float* gru_Whh = (const float*)d_in[12];
  const float* gru_bih = (const float*)d_in[13];
  const float* gru_bhh = (const float*)d_in[14];
  const float* pred_W = (const float*)d_in[15];
  const float* pred_b = (const float*)d_in[16];

  char* ws = (char*)d_ws;
  size_t off = 0;
  auto walloc = [&](size_t bytes) -> void* {
    void* p = ws + off;
    off = (off + bytes + 255) & ~(size_t)255;
    return p;
  };
  float* h = (float*)walloc((size_t)NV * D * 4);
  float* neigh = (float*)walloc((size_t)NV * D * 4);
  __hip_bfloat16* t_bf = (__hip_bfloat16*)walloc((size_t)NE * EHID * 2);
  __hip_bfloat16* w2_bf = (__hip_bfloat16*)walloc((size_t)D * D * EHID * 2);
  __hip_bfloat16* b2t = (__hip_bfloat16*)walloc((size_t)D * D * 2);
  __hip_bfloat16* Bhi = (__hip_bfloat16*)walloc((size_t)256 * 128 * 2);
  __hip_bfloat16* Blo = (__hip_bfloat16*)walloc((size_t)256 * 128 * 2);

  k_proj<<<NV / 4, 256, 0, stream>>>(node_feats, proj_W, proj_b, h, neigh);
  k_edge1<<<NE / 2, 256, 0, stream>>>(edge_feats, en_W1, en_b1, t_bf);
  k_cvt_w2<<<(D * D * EHID + 255) / 256, 256, 0, stream>>>(en_W2, w2_bf);
  k_b2t<<<(D * D + 255) / 256, 256, 0, stream>>>(en_b2, b2t);
  k_build_b<<<128, 256, 0, stream>>>(gru_Wih, gru_Whh, Bhi, Blo);
  for (int s = 0; s < NSTEPS; ++s) {
    k_msg<<<256, 512, 0, stream>>>(h, t_bf, w2_bf, b2t, src, dst, neigh);
    k_gru<<<NV / 32, 256, 0, stream>>>(neigh, h, Bhi, Blo, conv_b, gru_bih, gru_bhh);
  }
  k_pred<<<NE / 4, 256, 0, stream>>>(h, src, dst, pred_W, pred_b, (float*)d_out);
}